// Round 7
// baseline (88.813 us; speedup 1.0000x reference)
//
#include <hip/hip_runtime.h>
#include <stdint.h>

#define NPART 2048
#define FEPS 1e-12f
// JAX >= 0.5 defaults jax_threefry_partitionable=True (verified: absmax 0.0
// in R1/R2/R4). Legacy path kept behind this macro for reference.
#define PARTITIONABLE 1

__device__ __forceinline__ uint32_t rotl32(uint32_t v, uint32_t r) {
  return (v << r) | (v >> (32u - r));
}

// Threefry-2x32, 20 rounds (Random123 / JAX). KAT: key=(0,0),ctr=(0,0) ->
// (0x6b200159, 0x99ba4efe).
__device__ __forceinline__ void tf2x32(uint32_t k0, uint32_t k1,
                                       uint32_t x0, uint32_t x1,
                                       uint32_t& o0, uint32_t& o1) {
  uint32_t ks2 = k0 ^ k1 ^ 0x1BD11BDAu;
#define TF_RND(r) { x0 += x1; x1 = rotl32(x1, r); x1 ^= x0; }
  x0 += k0; x1 += k1;
  TF_RND(13u) TF_RND(15u) TF_RND(26u) TF_RND(6u)
  x0 += k1; x1 += ks2 + 1u;
  TF_RND(17u) TF_RND(29u) TF_RND(16u) TF_RND(24u)
  x0 += ks2; x1 += k0 + 2u;
  TF_RND(13u) TF_RND(15u) TF_RND(26u) TF_RND(6u)
  x0 += k0; x1 += k1 + 3u;
  TF_RND(17u) TF_RND(29u) TF_RND(16u) TF_RND(24u)
  x0 += k1; x1 += ks2 + 4u;
  TF_RND(13u) TF_RND(15u) TF_RND(26u) TF_RND(6u)
  x0 += ks2; x1 += k0 + 5u;
#undef TF_RND
  o0 = x0; o1 = x1;
}

__device__ __forceinline__ void split_first(uint32_t k0, uint32_t k1,
                                            uint32_t& o0, uint32_t& o1) {
#if PARTITIONABLE
  tf2x32(k0, k1, 0u, 0u, o0, o1);
#else
  uint32_t a0, a1, b0, b1;
  tf2x32(k0, k1, 0u, 2u, a0, a1);
  tf2x32(k0, k1, 1u, 3u, b0, b1);
  o0 = a0; o1 = b0;
#endif
}

__device__ __forceinline__ void split_at(uint32_t k0, uint32_t k1, uint32_t M,
                                         uint32_t r, uint32_t& o0, uint32_t& o1) {
#if PARTITIONABLE
  tf2x32(k0, k1, 0u, r, o0, o1);
#else
  uint32_t c0 = 2u * r, c1 = 2u * r + 1u;
  uint32_t a0, a1;
  if (c0 < M) { tf2x32(k0, k1, c0, c0 + M, a0, a1); o0 = a0; }
  else        { tf2x32(k0, k1, c0 - M, c0, a0, a1); o0 = a1; }
  if (c1 < M) { tf2x32(k0, k1, c1, c1 + M, a0, a1); o1 = a0; }
  else        { tf2x32(k0, k1, c1 - M, c1, a0, a1); o1 = a1; }
#endif
}

__device__ __forceinline__ uint32_t bits_at(uint32_t k0, uint32_t k1,
                                            uint32_t S_half, uint32_t idx) {
  uint32_t a0, a1;
#if PARTITIONABLE
  (void)S_half;
  tf2x32(k0, k1, 0u, idx, a0, a1);
  return a0 ^ a1;
#else
  if (idx < S_half) { tf2x32(k0, k1, idx, idx + S_half, a0, a1); return a0; }
  else              { tf2x32(k0, k1, idx - S_half, idx, a0, a1); return a1; }
#endif
}

__device__ __forceinline__ void derive_keys(int seed, uint32_t& g0, uint32_t& g1,
                                            uint32_t& s0, uint32_t& s1) {
  uint64_t sv = (uint64_t)(int64_t)seed;
  uint32_t k0 = (uint32_t)(sv >> 32), k1 = (uint32_t)sv;
  uint32_t a0, a1;
  split_first(k0, k1, a0, a1);      // skey1
  split_first(a0, a1, s0, s1);      // skey2
  split_first(s0, s1, g0, g1);      // gkey = split(skey2)[0]
}

// One 64-lane wave per row i; 4 waves/block, rows strided by 512 so block
// work is balanced.
__global__ __launch_bounds__(256) void phase1_choose(
    const float* __restrict__ pos, const float* __restrict__ rad,
    const int* __restrict__ seedp, int* __restrict__ chosen,
    float* __restrict__ pen_out) {
#pragma clang fp contract(off)
  const int lane = threadIdx.x & 63;
  const int i = blockIdx.x + 512 * (threadIdx.x >> 6);

  uint32_t g0, g1, s0, s1;
  derive_keys(seedp[0], g0, g1, s0, s1);
  uint32_t ki0, ki1;
  split_at(s0, s1, (uint32_t)NPART, (uint32_t)i, ki0, ki1);

  const float pix = pos[2 * i], piy = pos[2 * i + 1];
  const float ri = rad[i];

  unsigned long long best = 0ull;
  for (int j = lane; j < i; j += 64) {
    float2 pj = reinterpret_cast<const float2*>(pos)[j];
    float dx = pix - pj.x;
    float dy = piy - pj.y;
    float dist = sqrtf(dx * dx + dy * dy + FEPS);
    float pen = (ri + rad[j]) - dist;
    if (pen > 0.0f) {
      // bernoulli(0.5) gate: top bit of the 32-bit draw == 0
      uint32_t gb = bits_at(g0, g1, (uint32_t)NPART * NPART / 2u,
                            (uint32_t)(i * NPART + j));
      if ((gb >> 31) == 0u) {
        // categorical over equal logits == argmax of mantissa bits (b>>9);
        // first index wins ties (matches jnp.argmax).
        uint32_t b = bits_at(ki0, ki1, (uint32_t)NPART / 2u, (uint32_t)j);
        unsigned long long cand =
            ((unsigned long long)(b >> 9) << 32) |
            (uint32_t)(0xFFFFFFFFu - (uint32_t)j);
        if (cand > best) best = cand;
      }
    }
  }
  for (int off = 1; off < 64; off <<= 1) {
    unsigned long long o = __shfl_xor(best, off, 64);
    if (o > best) best = o;
  }
  if (lane == 0) {
    if (best == 0ull) {
      chosen[i] = -1;
      pen_out[2 * i] = 0.0f;
      pen_out[2 * i + 1] = 0.0f;
    } else {
      int j = (int)(0xFFFFFFFFu - (uint32_t)(best & 0xFFFFFFFFu));
      float2 pj = reinterpret_cast<const float2*>(pos)[j];
      float dx = pix - pj.x;
      float dy = piy - pj.y;
      float dist = sqrtf(dx * dx + dy * dy + FEPS);
      float pen = (ri + rad[j]) - dist;
      chosen[i] = j;
      pen_out[2 * i] = (dx / dist) * pen;   // normal*pen, exact ref order
      pen_out[2 * i + 1] = (dy / dist) * pen;
    }
  }
}

__global__ __launch_bounds__(256) void phase2_scan(
    const float* __restrict__ pos, const float* __restrict__ vel,
    const float* __restrict__ mass, const int* __restrict__ chosen,
    const float* __restrict__ pen, float* __restrict__ out) {
#pragma clang fp contract(off)
  __shared__ float2 pxy[NPART], vxy[NPART];
  __shared__ int ij[NPART];          // (i<<16)|j per contact, in row order
  __shared__ float4 PA[NPART];       // {Ax, Ay, Bx, By} = corr*imi / corr*imj
  __shared__ float4 PB[NPART];       // {nx, ny, imi, imj}; s = imi+imj (exact)
  __shared__ int minK[NPART];        // round-tagged argmin, init 0
  __shared__ int wsum[4];

  const int tid = threadIdx.x;
  const int lane = tid & 63, w = tid >> 6;

  for (int r = tid; r < NPART; r += 256) {
    pxy[r] = reinterpret_cast<const float2*>(pos)[r];
    vxy[r] = reinterpret_cast<const float2*>(vel)[r];
    minK[r] = 0;
  }

  // ---- ordered compaction: thread t owns rows [8t,8t+8); wave shfl-scan ----
  const int base = tid * 8;
  int4 c0 = reinterpret_cast<const int4*>(chosen)[2 * tid];
  int4 c1 = reinterpret_cast<const int4*>(chosen)[2 * tid + 1];
  int loc[8] = {c0.x, c0.y, c0.z, c0.w, c1.x, c1.y, c1.z, c1.w};
  int c = 0;
#pragma unroll
  for (int t = 0; t < 8; ++t) c += (loc[t] >= 0);

  int incl = c;
#pragma unroll
  for (int off = 1; off < 64; off <<= 1) {
    int v = __shfl_up(incl, off, 64);
    if (lane >= off) incl += v;
  }
  if (lane == 63) wsum[w] = incl;
  __syncthreads();
  int woff = 0, K = 0;
#pragma unroll
  for (int q = 0; q < 4; ++q) {
    int s = wsum[q];
    if (q < w) woff += s;
    K += s;
  }
  {
    int wr = woff + incl - c;
#pragma unroll
    for (int t = 0; t < 8; ++t) {
      if (loc[t] >= 0) { ij[wr] = ((base + t) << 16) | loc[t]; wr++; }
    }
  }
  __syncthreads();

  // ---- per-contact params, exact reference rounding order ----
  for (int k = tid; k < K; k += 256) {
    int pr = ij[k];
    int i = pr >> 16, j = pr & 0xFFFF;
    float imi = 1.0f / mass[i];
    float imj = 1.0f / mass[j];
    float s = imi + imj;
    float pvx = pen[2 * i], pvy = pen[2 * i + 1];
    float nn = sqrtf(pvx * pvx + pvy * pvy + FEPS);
    PA[k] = make_float4((pvx / s) * imi, (pvy / s) * imi,
                        (pvx / s) * imj, (pvy / s) * imj);
    PB[k] = make_float4(pvx / nn, pvy / nn, imi, imj);
  }
  __syncthreads();

  // ---- level-synchronous rounds on a SINGLE wave. Lane l owns contacts
  // k = r*64+l, with (i,j) cached in REGISTERS (statically unrolled — no
  // per-round ij re-reads, the R4 bottleneck). Contact k fires iff it is the
  // minimum active contact for BOTH endpoints this round: same-round fires
  // are particle-disjoint and per-particle order is preserved => bit-identical
  // to the reference serial scan (R1/R2/R4: absmax 0.0).
  // Round tags: tag = (round<<12)|(4095-k); atomicMax prefers current round,
  // then smallest k — stale entries lose automatically, no reset pass.
  if (w == 0) {
    int prc[32];
    uint32_t act = 0;
    {
      const int nR = (K + 63) >> 6;
#pragma unroll
      for (int r = 0; r < 32; ++r) {
        int k = r * 64 + lane;
        if (r < nR && k < K) { prc[r] = ij[k]; act |= (1u << r); }
        else prc[r] = 0;
      }
    }

    for (int round = 1; __any(act); ++round) {
      const int tagbase = round << 12;
      // phase A: publish candidacy (register-sourced addresses, one drain)
#pragma unroll
      for (int r = 0; r < 32; ++r) {
        if (act & (1u << r)) {
          int tag = tagbase | (4095 - (r * 64 + lane));
          atomicMax(&minK[prc[r] >> 16], tag);
          atomicMax(&minK[prc[r] & 0xFFFF], tag);
        }
      }
      __threadfence_block();
      // phase B1: batched winner reads (independent -> pipelined)
      int mi[32], mj[32];
#pragma unroll
      for (int r = 0; r < 32; ++r) {
        if (act & (1u << r)) {
          mi[r] = minK[prc[r] >> 16];
          mj[r] = minK[prc[r] & 0xFFFF];
        }
      }
      // phase B2: fire winners (same-round fires are particle-disjoint)
#pragma unroll
      for (int r = 0; r < 32; ++r) {
        if (act & (1u << r)) {
          int tag = tagbase | (4095 - (r * 64 + lane));
          if (mi[r] == tag && mj[r] == tag) {
            int k = r * 64 + lane;
            int i = prc[r] >> 16, j = prc[r] & 0xFFFF;
            float4 pa = PA[k], pb = PB[k];
            float2 pi = pxy[i], pj = pxy[j];
            pxy[i] = make_float2(pi.x + pa.x, pi.y + pa.y);
            pxy[j] = make_float2(pj.x - pa.z, pj.y - pa.w);
            float2 vi = vxy[i], vj = vxy[j];
            float rx = vi.x - vj.x, ry = vi.y - vj.y;
            float vrel = rx * pb.x + ry * pb.y;
            if (vrel < 0.0f) {
              float s = pb.z + pb.w;           // imi+imj, bit-identical
              float jimp = (-1.5f * vrel) / s;
              float ji = jimp * pb.z, jj = jimp * pb.w;
              vxy[i] = make_float2(vi.x + ji * pb.x, vi.y + ji * pb.y);
              vxy[j] = make_float2(vj.x - jj * pb.x, vj.y - jj * pb.y);
            }
            // vrel >= 0: jimp = 0 -> velocities bit-unchanged in the ref
            act &= ~(1u << r);
          }
        }
      }
      __threadfence_block();
      if (round > 4096) break;   // safety; provably unreachable
    }
  }
  __syncthreads();

  for (int r = tid; r < NPART; r += 256) {
    float2 p2 = pxy[r], v2 = vxy[r];
    reinterpret_cast<float4*>(out)[r] = make_float4(p2.x, p2.y, v2.x, v2.y);
  }
}

extern "C" void kernel_launch(void* const* d_in, const int* in_sizes, int n_in,
                              void* d_out, int out_size, void* d_ws, size_t ws_size,
                              hipStream_t stream) {
  const float* pos = (const float*)d_in[0];
  const float* rad = (const float*)d_in[1];
  const float* vel = (const float*)d_in[2];
  const float* mass = (const float*)d_in[3];
  const int* seed = (const int*)d_in[4];

  int* chosen = (int*)d_ws;
  float* pen = (float*)((char*)d_ws + NPART * sizeof(int));

  phase1_choose<<<dim3(512), dim3(256), 0, stream>>>(pos, rad, seed, chosen, pen);
  phase2_scan<<<dim3(1), dim3(256), 0, stream>>>(pos, vel, mass, chosen, pen,
                                                 (float*)d_out);
}

// Round 8
// 79.447 us; speedup vs baseline: 1.1179x; 1.1179x over previous
//
#include <hip/hip_runtime.h>
#include <stdint.h>

#define NPART 2048
#define FEPS 1e-12f
// JAX >= 0.5 defaults jax_threefry_partitionable=True (verified: absmax 0.0
// in R1/R2/R4/R7). Legacy path kept behind this macro for reference.
#define PARTITIONABLE 1

__device__ __forceinline__ uint32_t rotl32(uint32_t v, uint32_t r) {
  return (v << r) | (v >> (32u - r));
}

// Threefry-2x32, 20 rounds (Random123 / JAX). KAT: key=(0,0),ctr=(0,0) ->
// (0x6b200159, 0x99ba4efe).
__device__ __forceinline__ void tf2x32(uint32_t k0, uint32_t k1,
                                       uint32_t x0, uint32_t x1,
                                       uint32_t& o0, uint32_t& o1) {
  uint32_t ks2 = k0 ^ k1 ^ 0x1BD11BDAu;
#define TF_RND(r) { x0 += x1; x1 = rotl32(x1, r); x1 ^= x0; }
  x0 += k0; x1 += k1;
  TF_RND(13u) TF_RND(15u) TF_RND(26u) TF_RND(6u)
  x0 += k1; x1 += ks2 + 1u;
  TF_RND(17u) TF_RND(29u) TF_RND(16u) TF_RND(24u)
  x0 += ks2; x1 += k0 + 2u;
  TF_RND(13u) TF_RND(15u) TF_RND(26u) TF_RND(6u)
  x0 += k0; x1 += k1 + 3u;
  TF_RND(17u) TF_RND(29u) TF_RND(16u) TF_RND(24u)
  x0 += k1; x1 += ks2 + 4u;
  TF_RND(13u) TF_RND(15u) TF_RND(26u) TF_RND(6u)
  x0 += ks2; x1 += k0 + 5u;
#undef TF_RND
  o0 = x0; o1 = x1;
}

__device__ __forceinline__ void split_first(uint32_t k0, uint32_t k1,
                                            uint32_t& o0, uint32_t& o1) {
#if PARTITIONABLE
  tf2x32(k0, k1, 0u, 0u, o0, o1);
#else
  uint32_t a0, a1, b0, b1;
  tf2x32(k0, k1, 0u, 2u, a0, a1);
  tf2x32(k0, k1, 1u, 3u, b0, b1);
  o0 = a0; o1 = b0;
#endif
}

__device__ __forceinline__ void split_at(uint32_t k0, uint32_t k1, uint32_t M,
                                         uint32_t r, uint32_t& o0, uint32_t& o1) {
#if PARTITIONABLE
  tf2x32(k0, k1, 0u, r, o0, o1);
#else
  uint32_t c0 = 2u * r, c1 = 2u * r + 1u;
  uint32_t a0, a1;
  if (c0 < M) { tf2x32(k0, k1, c0, c0 + M, a0, a1); o0 = a0; }
  else        { tf2x32(k0, k1, c0 - M, c0, a0, a1); o0 = a1; }
  if (c1 < M) { tf2x32(k0, k1, c1, c1 + M, a0, a1); o1 = a0; }
  else        { tf2x32(k0, k1, c1 - M, c1, a0, a1); o1 = a1; }
#endif
}

__device__ __forceinline__ uint32_t bits_at(uint32_t k0, uint32_t k1,
                                            uint32_t S_half, uint32_t idx) {
  uint32_t a0, a1;
#if PARTITIONABLE
  (void)S_half;
  tf2x32(k0, k1, 0u, idx, a0, a1);
  return a0 ^ a1;
#else
  if (idx < S_half) { tf2x32(k0, k1, idx, idx + S_half, a0, a1); return a0; }
  else              { tf2x32(k0, k1, idx - S_half, idx, a0, a1); return a1; }
#endif
}

__device__ __forceinline__ void derive_keys(int seed, uint32_t& g0, uint32_t& g1,
                                            uint32_t& s0, uint32_t& s1) {
  uint64_t sv = (uint64_t)(int64_t)seed;
  uint32_t k0 = (uint32_t)(sv >> 32), k1 = (uint32_t)sv;
  uint32_t a0, a1;
  split_first(k0, k1, a0, a1);      // skey1
  split_first(a0, a1, s0, s1);      // skey2
  split_first(s0, s1, g0, g1);      // gkey = split(skey2)[0]
}

// One 64-lane wave per row i; 4 waves/block, rows strided by 512 so block
// work is balanced.
__global__ __launch_bounds__(256) void phase1_choose(
    const float* __restrict__ pos, const float* __restrict__ rad,
    const int* __restrict__ seedp, int* __restrict__ chosen,
    float* __restrict__ pen_out) {
#pragma clang fp contract(off)
  const int lane = threadIdx.x & 63;
  const int i = blockIdx.x + 512 * (threadIdx.x >> 6);

  uint32_t g0, g1, s0, s1;
  derive_keys(seedp[0], g0, g1, s0, s1);
  uint32_t ki0, ki1;
  split_at(s0, s1, (uint32_t)NPART, (uint32_t)i, ki0, ki1);

  const float pix = pos[2 * i], piy = pos[2 * i + 1];
  const float ri = rad[i];

  unsigned long long best = 0ull;
  for (int j = lane; j < i; j += 64) {
    float2 pj = reinterpret_cast<const float2*>(pos)[j];
    float dx = pix - pj.x;
    float dy = piy - pj.y;
    float dist = sqrtf(dx * dx + dy * dy + FEPS);
    float pen = (ri + rad[j]) - dist;
    if (pen > 0.0f) {
      // bernoulli(0.5) gate: top bit of the 32-bit draw == 0
      uint32_t gb = bits_at(g0, g1, (uint32_t)NPART * NPART / 2u,
                            (uint32_t)(i * NPART + j));
      if ((gb >> 31) == 0u) {
        // categorical over equal logits == argmax of mantissa bits (b>>9);
        // first index wins ties (matches jnp.argmax).
        uint32_t b = bits_at(ki0, ki1, (uint32_t)NPART / 2u, (uint32_t)j);
        unsigned long long cand =
            ((unsigned long long)(b >> 9) << 32) |
            (uint32_t)(0xFFFFFFFFu - (uint32_t)j);
        if (cand > best) best = cand;
      }
    }
  }
  for (int off = 1; off < 64; off <<= 1) {
    unsigned long long o = __shfl_xor(best, off, 64);
    if (o > best) best = o;
  }
  if (lane == 0) {
    if (best == 0ull) {
      chosen[i] = -1;
      pen_out[2 * i] = 0.0f;
      pen_out[2 * i + 1] = 0.0f;
    } else {
      int j = (int)(0xFFFFFFFFu - (uint32_t)(best & 0xFFFFFFFFu));
      float2 pj = reinterpret_cast<const float2*>(pos)[j];
      float dx = pix - pj.x;
      float dy = piy - pj.y;
      float dist = sqrtf(dx * dx + dy * dy + FEPS);
      float pen = (ri + rad[j]) - dist;
      chosen[i] = j;
      pen_out[2 * i] = (dx / dist) * pen;   // normal*pen, exact ref order
      pen_out[2 * i + 1] = (dy / dist) * pen;
    }
  }
}

__global__ __launch_bounds__(256) void phase2_scan(
    const float* __restrict__ pos, const float* __restrict__ vel,
    const float* __restrict__ mass, const int* __restrict__ chosen,
    const float* __restrict__ pen, float* __restrict__ out) {
#pragma clang fp contract(off)
  __shared__ float2 pxy[NPART], vxy[NPART];
  __shared__ int ij[NPART];          // (i<<16)|j per contact, in row order
  __shared__ float4 PA[NPART];       // {Ax, Ay, Bx, By} = corr*imi / corr*imj
  __shared__ float4 PB[NPART];       // {nx, ny, imi, imj}; s = imi+imj (exact)
  __shared__ int minK[NPART];        // round-tagged argmin, init 0
  __shared__ int wsum[4];

  const int tid = threadIdx.x;
  const int lane = tid & 63, w = tid >> 6;

  for (int r = tid; r < NPART; r += 256) {
    pxy[r] = reinterpret_cast<const float2*>(pos)[r];
    vxy[r] = reinterpret_cast<const float2*>(vel)[r];
    minK[r] = 0;
  }

  // ---- ordered compaction: thread t owns rows [8t,8t+8); wave shfl-scan ----
  const int base = tid * 8;
  int4 c0 = reinterpret_cast<const int4*>(chosen)[2 * tid];
  int4 c1 = reinterpret_cast<const int4*>(chosen)[2 * tid + 1];
  int loc[8] = {c0.x, c0.y, c0.z, c0.w, c1.x, c1.y, c1.z, c1.w};
  int c = 0;
#pragma unroll
  for (int t = 0; t < 8; ++t) c += (loc[t] >= 0);

  int incl = c;
#pragma unroll
  for (int off = 1; off < 64; off <<= 1) {
    int v = __shfl_up(incl, off, 64);
    if (lane >= off) incl += v;
  }
  if (lane == 63) wsum[w] = incl;
  __syncthreads();
  int woff = 0, K = 0;
#pragma unroll
  for (int q = 0; q < 4; ++q) {
    int s = wsum[q];
    if (q < w) woff += s;
    K += s;
  }
  {
    int wr = woff + incl - c;
#pragma unroll
    for (int t = 0; t < 8; ++t) {
      if (loc[t] >= 0) { ij[wr] = ((base + t) << 16) | loc[t]; wr++; }
    }
  }
  __syncthreads();

  // ---- per-contact params, exact reference rounding order ----
  for (int k = tid; k < K; k += 256) {
    int pr = ij[k];
    int i = pr >> 16, j = pr & 0xFFFF;
    float imi = 1.0f / mass[i];
    float imj = 1.0f / mass[j];
    float s = imi + imj;
    float pvx = pen[2 * i], pvy = pen[2 * i + 1];
    float nn = sqrtf(pvx * pvx + pvy * pvy + FEPS);
    PA[k] = make_float4((pvx / s) * imi, (pvy / s) * imi,
                        (pvx / s) * imj, (pvy / s) * imj);
    PB[k] = make_float4(pvx / nn, pvy / nn, imi, imj);
  }
  __syncthreads();

  // ---- level-synchronous rounds across ALL 4 WAVES. Thread t owns contacts
  // k = r*256 + t (r<8 => 24 registers, no spill — the R7 suspect). Contact k
  // fires iff it is the minimum active contact for BOTH endpoints this round:
  // same-round fires are particle-disjoint and per-particle order is
  // preserved => bit-identical to the reference serial scan (absmax 0.0 in
  // R1/R2/R4/R7). Tags: tag = (round<<12)|(4095-k); atomicMax prefers the
  // current round, then the smallest k — stale entries lose, no reset pass.
  // Progress: the globally smallest active k wins both endpoints each round.
  int prc[8];
  uint32_t act = 0;
#pragma unroll
  for (int r = 0; r < 8; ++r) {
    int k = r * 256 + tid;
    if (k < K) { prc[r] = ij[k]; act |= (1u << r); }
    else prc[r] = 0;
  }

  for (int round = 1; __syncthreads_or(act != 0); ++round) {
    const int tagbase = round << 12;
    // phase A: publish candidacy (register-sourced addresses)
#pragma unroll
    for (int r = 0; r < 8; ++r) {
      if (act & (1u << r)) {
        int tag = tagbase | (4095 - (r * 256 + tid));
        atomicMax(&minK[prc[r] >> 16], tag);
        atomicMax(&minK[prc[r] & 0xFFFF], tag);
      }
    }
    __syncthreads();
    // phase B: batched winner reads (independent -> pipelined), then fire
    int mi[8], mj[8];
#pragma unroll
    for (int r = 0; r < 8; ++r) {
      if (act & (1u << r)) {
        mi[r] = minK[prc[r] >> 16];
        mj[r] = minK[prc[r] & 0xFFFF];
      }
    }
#pragma unroll
    for (int r = 0; r < 8; ++r) {
      if (act & (1u << r)) {
        int k = r * 256 + tid;
        int tag = tagbase | (4095 - k);
        if (mi[r] == tag && mj[r] == tag) {
          int i = prc[r] >> 16, j = prc[r] & 0xFFFF;
          float4 pa = PA[k], pb = PB[k];
          float2 pi = pxy[i], pj = pxy[j];
          pxy[i] = make_float2(pi.x + pa.x, pi.y + pa.y);
          pxy[j] = make_float2(pj.x - pa.z, pj.y - pa.w);
          float2 vi = vxy[i], vj = vxy[j];
          float rx = vi.x - vj.x, ry = vi.y - vj.y;
          float vrel = rx * pb.x + ry * pb.y;
          if (vrel < 0.0f) {
            float s = pb.z + pb.w;           // imi+imj, bit-identical
            float jimp = (-1.5f * vrel) / s;
            float ji = jimp * pb.z, jj = jimp * pb.w;
            vxy[i] = make_float2(vi.x + ji * pb.x, vi.y + ji * pb.y);
            vxy[j] = make_float2(vj.x - jj * pb.x, vj.y - jj * pb.y);
          }
          // vrel >= 0: jimp = 0 -> velocities bit-unchanged in the ref
          act &= ~(1u << r);
        }
      }
    }
    // loop-head __syncthreads_or separates this round's fires from the
    // next round's phase A (and re-converges all 256 threads).
  }

  for (int r = tid; r < NPART; r += 256) {
    float2 p2 = pxy[r], v2 = vxy[r];
    reinterpret_cast<float4*>(out)[r] = make_float4(p2.x, p2.y, v2.x, v2.y);
  }
}

extern "C" void kernel_launch(void* const* d_in, const int* in_sizes, int n_in,
                              void* d_out, int out_size, void* d_ws, size_t ws_size,
                              hipStream_t stream) {
  const float* pos = (const float*)d_in[0];
  const float* rad = (const float*)d_in[1];
  const float* vel = (const float*)d_in[2];
  const float* mass = (const float*)d_in[3];
  const int* seed = (const int*)d_in[4];

  int* chosen = (int*)d_ws;
  float* pen = (float*)((char*)d_ws + NPART * sizeof(int));

  phase1_choose<<<dim3(512), dim3(256), 0, stream>>>(pos, rad, seed, chosen, pen);
  phase2_scan<<<dim3(1), dim3(256), 0, stream>>>(pos, vel, mass, chosen, pen,
                                                 (float*)d_out);
}